// Round 19
// baseline (176.898 us; speedup 1.0000x reference)
//
#include <hip/hip_runtime.h>
#include <hip/hip_fp16.h>

typedef _Float16 half8 __attribute__((ext_vector_type(8)));
typedef _Float16 half4 __attribute__((ext_vector_type(4)));
typedef _Float16 half2v __attribute__((ext_vector_type(2)));
typedef float f32x4 __attribute__((ext_vector_type(4)));
typedef float f32x8v __attribute__((ext_vector_type(8)));
typedef float f32x16 __attribute__((ext_vector_type(16)));

#define SEQ   2048
#define DM    1024
#define NH    16
#define HD    64
#define BSZ   4

#if __has_builtin(__builtin_amdgcn_exp2f)
#define EXP2(x) __builtin_amdgcn_exp2f(x)
#else
#define EXP2(x) exp2f(x)
#endif

// Q pre-scale: (1/sqrt(64)) * log2(e)  -> scores land in log2 domain
#define QSCALE 0.1803368801f
// log2(10000)/32
#define ROPE_C 0.41524101186f

// async global->LDS, 16B per lane. LDS dest = wave-uniform base + lane*16.
__device__ __forceinline__ void gload16(const void* g, void* l) {
  __builtin_amdgcn_global_load_lds((const __attribute__((address_space(1))) void*)g,
                                   (__attribute__((address_space(3))) void*)l,
                                   16, 0, 0);
}

// ---------------- fp32 -> fp16 convert: x + all 4 weights in ONE launch -------------
__global__ void cvtAll(const float* __restrict__ x,
                       const float* __restrict__ s0, const float* __restrict__ s1,
                       const float* __restrict__ s2, const float* __restrict__ s3,
                       _Float16* __restrict__ xh, _Float16* __restrict__ dqkv,
                       _Float16* __restrict__ dO) {
  const int i = blockIdx.x * blockDim.x + threadIdx.x;
  const float* src;
  _Float16* dst;
  int idx;
  if (i < 2097152) {
    src = x; dst = xh; idx = i;
  } else {
    const int j = i - 2097152;
    const int which = j >> 18;            // 0..3
    idx = j & 262143;
    src = (which == 0) ? s0 : (which == 1) ? s1 : (which == 2) ? s2 : s3;
    dst = (which < 3) ? (dqkv + (long)which * (1u << 20)) : dO;
  }
  float4 v = ((const float4*)src)[idx];
  half4 o = { (_Float16)v.x, (_Float16)v.y, (_Float16)v.z, (_Float16)v.w };
  ((half4*)dst)[idx] = o;
}

// ---------------- GEMM: C = A * B^T, A[M][1024] f16, B[N][1024] f16 ----------------
// r15/r18 best-known config: 128x128 tile, 4 waves (2x2), BK=32, 16x16x32 f16 MFMA,
// 2-phase 32KB double-buffer (4 blocks/CU) + r12 zero-conflict slab swizzle
// (BANK_CONFLICT=0 verified). Campaign r11-r16 established ~700TF as this K=1024
// shape's practical plateau (2-barrier-loop structure ceiling, cf. guide m230).
// MODE 0: QKV epilogue with FUSED RoPE -> Q(scaled)[bh][s][64], K[bh][s][64],
//         Vt[bh][64][s] (f16).  MODE 1: plain f32 store to out[M][1024]
template<int MODE>
__global__ __launch_bounds__(256)
void gemm_hk(const _Float16* __restrict__ A, const _Float16* __restrict__ B,
             _Float16* __restrict__ oQ, _Float16* __restrict__ oK,
             _Float16* __restrict__ oVt, float* __restrict__ oF,
             const int* __restrict__ tp) {
  __shared__ _Float16 As[2][128*32];
  __shared__ _Float16 Bs[2][128*32];
  const int tid  = threadIdx.x;
  const int wid  = tid >> 6, lane = tid & 63;
  const int wm   = wid >> 1, wn = wid & 1;
  const int fr   = lane & 15, fg = lane >> 4;
  const long m0  = (long)blockIdx.x * 128;
  const long n0  = (long)blockIdx.y * 128;
  const int sg    = (lane & 7) ^ ((lane >> 3) & 7);
  const int srowl = 2*(lane >> 3) + (sg >> 2);      // row within 16-row group
  const int scol  = (sg & 3) * 8;                   // halfs
  const _Float16* ga0 = A + (m0 + wid*32 + srowl) * 1024 + scol;
  const _Float16* gb0 = B + (n0 + wid*32 + srowl) * 1024 + scol;
  const int lofs = wid*32*32;

  f32x4 acc[4][4] = {};

  auto ldfrag = [&](const char* base, int R) -> half8 {
    const int r = R & 31, r2 = r >> 1;
    return *(const half8*)(base + (R >> 5)*2048 + r2*128 +
                           (((((r & 1) << 2) | fg) ^ (r2 & 7)) << 4));
  };

  // prologue: stage k0=0 into buf 0
  gload16(ga0,           &As[0][lofs]);
  gload16(ga0 + 16*1024, &As[0][lofs + 16*32]);
  gload16(gb0,           &Bs[0][lofs]);
  gload16(gb0 + 16*1024, &Bs[0][lofs + 16*32]);
  __syncthreads();

  int cur = 0;
  for (int k0 = 0; k0 < 1024; k0 += 32) {
    if (k0 + 32 < 1024) {
      gload16(ga0 + k0 + 32,           &As[cur^1][lofs]);
      gload16(ga0 + k0 + 32 + 16*1024, &As[cur^1][lofs + 16*32]);
      gload16(gb0 + k0 + 32,           &Bs[cur^1][lofs]);
      gload16(gb0 + k0 + 32 + 16*1024, &Bs[cur^1][lofs + 16*32]);
    }
    const char* Ab = (const char*)&As[cur][0];
    const char* Bb = (const char*)&Bs[cur][0];
    half8 af[4], bf[4];
#pragma unroll
    for (int i = 0; i < 4; ++i) {
      af[i] = ldfrag(Ab, wm*64 + i*16 + fr);
      bf[i] = ldfrag(Bb, wn*64 + i*16 + fr);
    }
    __builtin_amdgcn_s_setprio(1);
#pragma unroll
    for (int i = 0; i < 4; ++i)
#pragma unroll
      for (int j = 0; j < 4; ++j)
        acc[i][j] = __builtin_amdgcn_mfma_f32_16x16x32_f16(af[i], bf[j], acc[i][j], 0, 0, 0);
    __builtin_amdgcn_s_setprio(0);
    __syncthreads();
    cur ^= 1;
  }

  if (MODE == 0) {
    const int which = (int)(n0 >> 10);
    const int nloc0 = ((int)n0 & 1023) + wn*64;
    const bool odd = fr & 1;
#pragma unroll
    for (int i = 0; i < 4; ++i) {
      const long r0 = m0 + wm*64 + i*16 + fg*4;
      const int  bb = (int)(r0 >> 11);
      const int  s  = (int)(r0 & 2047);
#pragma unroll
      for (int j = 0; j < 4; ++j) {
        const int nl = nloc0 + j*16 + fr;
        const int h  = nl >> 6, d = nl & 63;
        const long bh = (long)(bb*NH + h);
        if (which == 2) {
          half4 pk = { (_Float16)acc[i][j][0], (_Float16)acc[i][j][1],
                       (_Float16)acc[i][j][2], (_Float16)acc[i][j][3] };
          *(half4*)&oVt[(bh*HD + d)*SEQ + s] = pk;   // s % 4 == 0, 8B aligned
        } else {
          // fused RoPE: pair (2k,2k+1) lives in lanes (fr, fr^1), same (i,j,r)
          const float inv = exp2f(-ROPE_C * (float)(d >> 1));
#pragma unroll
          for (int r = 0; r < 4; ++r) {
            const float v = acc[i][j][r];
            const float p = __shfl_xor(v, 1);
            float sn, cs;
            __sincosf((float)tp[s + r] * inv, &sn, &cs);
            const float out = odd ? (v*cs + p*sn) : (v*cs - p*sn);
            if (which == 0)
              oQ[(bh*SEQ + s + r)*HD + d] = (_Float16)(out * QSCALE);
            else
              oK[(bh*SEQ + s + r)*HD + d] = (_Float16)out;
          }
        }
      }
    }
  } else {
#pragma unroll
    for (int i = 0; i < 4; ++i) {
      const long r0 = m0 + wm*64 + i*16 + fg*4;
#pragma unroll
      for (int j = 0; j < 4; ++j) {
        const long col = n0 + wn*64 + j*16 + fr;
#pragma unroll
        for (int r = 0; r < 4; ++r)
          oF[(r0 + r)*DM + col] = acc[i][j][r];
      }
    }
  }
}

// ---------------- causal flash attention (r19: 2-wave blocks, 5 blocks/CU) ----------
// grid (BH=64, 16 pairs), 128 threads (2 waves). Wave = 32 heavy + 32 light q-rows:
// heavy tile (31-y)*64, light tile y*64 — per-block weight (32-y)+(y+1) = 33 units,
// constant -> all 1024 equal blocks co-resident (5 blocks/CU by 32KB LDS, 10
// waves/CU vs r18's grid-capped 8). Verified 32x32 swapped P-in-register math
// unchanged: S^T = mfma(K,Q) with K rows via PI(m)=swap bits 2,3 -> lane (q31,hi)
// reg r = 8*ks+i holds S[kv = kvb + i + 8*hi + 16*ks] = PV B-fragment layout.
// Mask relabel: kvl(r,hi) = (r&3)+4*((r>>2)&1)+8*hi+16*(r>>3).
// Each wave stages 32 K-rows + 32 V-rows per tile (8 gloads, sc16 pre-swizzle).
__global__ __launch_bounds__(128, 2)
void fattn(const _Float16* __restrict__ Q, const _Float16* __restrict__ K,
           const _Float16* __restrict__ Vt, _Float16* __restrict__ O) {
  __shared__ _Float16 Ks[2][64*64];
  __shared__ _Float16 Vs[2][64*64];
  const int tid = threadIdx.x, wid = tid >> 6, lane = tid & 63;
  const int q31 = lane & 31, hi = lane >> 5;
  const int qp  = (q31 & 19) | ((q31 & 4) << 1) | ((q31 & 8) >> 1);  // swap bits 2,3
  const int bh = blockIdx.x, b = bh >> 4, h = bh & 15;
  const int y = blockIdx.y;              // 0..15
  const int qs_[2] = { (31 - y)*64 + wid*32, y*64 + wid*32 };
  const _Float16* Qb = Q + (long)bh * SEQ * HD;
  const _Float16* Kb = K + (long)bh * SEQ * HD;
  const _Float16* Vb = Vt + (long)bh * HD * SEQ;

  half8 qf[2][4];                        // [set][d-chunk16]
#pragma unroll
  for (int s = 0; s < 2; ++s)
#pragma unroll
    for (int c = 0; c < 4; ++c)
      qf[s][c] = *(const half8*)&Qb[(qs_[s] + q31)*HD + c*16 + hi*8];

  f32x16 oacc[2][2] = {};                // [set][nd]
  float m_s[2] = { -1e30f, -1e30f }, l_s[2] = { 0.f, 0.f };

  const int srow = lane >> 3;                 // 0..7
  const int sc16 = (lane & 7) ^ srow;         // pre-swizzled source slot
  const int rb = wid*32 + srow;               // this wave stages rows rb, +8, +16, +24

  const int nt = 32 - y;                      // kv tiles of 64 (heavy set drives)

  // prologue: stage tile 0 into buf 0 (each wave: 4 K-gloads + 4 V-gloads)
#pragma unroll
  for (int g = 0; g < 4; ++g) {
    gload16(Kb + (long)(rb + 8*g)*HD + sc16*8,  &Ks[0][(wid*32 + 8*g)*64]);
    gload16(Vb + (long)(rb + 8*g)*SEQ + sc16*8, &Vs[0][(wid*32 + 8*g)*64]);
  }
  __syncthreads();

  int cur = 0;
  for (int t = 0; t < nt; ++t) {
    const int kv0 = t * 64;

    // prefetch next tile (drained by end-of-tile barrier -> latency hidden)
    if (t + 1 < nt) {
      const int nkv = kv0 + 64;
#pragma unroll
      for (int g = 0; g < 4; ++g) {
        gload16(Kb + (long)(nkv + rb + 8*g)*HD + sc16*8,  &Ks[cur^1][(wid*32 + 8*g)*64]);
        gload16(Vb + (long)(rb + 8*g)*SEQ + nkv + sc16*8, &Vs[cur^1][(wid*32 + 8*g)*64]);
      }
    }

    const char* Kc = (const char*)&Ks[cur][0];
    const char* Vc = (const char*)&Vs[cur][0];

#pragma unroll
    for (int hh = 0; hh < 2; ++hh) {
      const int kvb = kv0 + 32*hh;
#pragma unroll
      for (int s = 0; s < 2; ++s) {
        const int qs0 = qs_[s];
        if (kvb > qs0 + 31) continue;

        f32x16 sa = {};
        __builtin_amdgcn_s_setprio(1);
#pragma unroll
        for (int c = 0; c < 4; ++c) {
          const int row = 32*hh + qp;
          const half8 kf = *(const half8*)(Kc + row*128 + ((c*32 + hi*16) ^ ((row & 7) << 4)));
          sa = __builtin_amdgcn_mfma_f32_32x32x16_f16(kf, qf[s][c], sa, 0, 0, 0);
        }
        __builtin_amdgcn_s_setprio(0);

        if (kvb + 31 > qs0) {
          const int thr = qs0 + q31 - kvb - 8*hi;
#pragma unroll
          for (int r = 0; r < 16; ++r) {
            const int cr = (r & 3) + 4*((r >> 2) & 1) + 16*(r >> 3);
            if (cr > thr) sa[r] = -1e30f;
          }
        }

        f32x8v mx8;
#pragma unroll
        for (int i = 0; i < 8; ++i) mx8[i] = fmaxf(sa[i], sa[i+8]);
        f32x4 mx4;
#pragma unroll
        for (int i = 0; i < 4; ++i) mx4[i] = fmaxf(mx8[i], mx8[i+4]);
        float pm = fmaxf(fmaxf(mx4[0], mx4[1]), fmaxf(mx4[2], mx4[3]));
        pm = fmaxf(pm, __shfl_xor(pm, 32));

        if (!__all(pm <= m_s[s] + 8.0f)) {
          const float mn = fmaxf(m_s[s], pm);
          const float fac = EXP2(m_s[s] - mn);
          m_s[s] = mn;
          l_s[s] *= fac;
          oacc[s][0] *= fac;
          oacc[s][1] *= fac;
        }
        const float mrow = m_s[s];

#pragma unroll
        for (int r = 0; r < 16; ++r) sa[r] = EXP2(sa[r] - mrow);

        f32x8v s8;
#pragma unroll
        for (int i = 0; i < 8; ++i) s8[i] = sa[i] + sa[i+8];
        f32x4 s4v;
#pragma unroll
        for (int i = 0; i < 4; ++i) s4v[i] = s8[i] + s8[i+4];
        float ps = (s4v[0] + s4v[1]) + (s4v[2] + s4v[3]);
        ps += __shfl_xor(ps, 32);
        l_s[s] += ps;

        half8 pf0, pf1;
#pragma unroll
        for (int g = 0; g < 4; ++g) {
          half2v t0 = (half2v)__builtin_amdgcn_cvt_pkrtz(sa[2*g],   sa[2*g+1]);
          half2v t1 = (half2v)__builtin_amdgcn_cvt_pkrtz(sa[8+2*g], sa[8+2*g+1]);
          pf0[2*g]   = t0[0];  pf0[2*g+1] = t0[1];
          pf1[2*g]   = t1[0];  pf1[2*g+1] = t1[1];
        }

        __builtin_amdgcn_s_setprio(1);
#pragma unroll
        for (int ks = 0; ks < 2; ++ks) {
          const half8 pf = ks ? pf1 : pf0;
#pragma unroll
          for (int nd = 0; nd < 2; ++nd) {
            const int row = nd*32 + q31;
            const half8 vf = *(const half8*)(Vc + row*128 +
                              ((hh*64 + ks*32 + hi*16) ^ ((row & 7) << 4)));
            oacc[s][nd] = __builtin_amdgcn_mfma_f32_32x32x16_f16(vf, pf, oacc[s][nd], 0, 0, 0);
          }
        }
        __builtin_amdgcn_s_setprio(0);
      }
    }

    __syncthreads();
    cur ^= 1;
  }

#pragma unroll
  for (int s = 0; s < 2; ++s) {
    const float rl = __builtin_amdgcn_rcpf(l_s[s]);
    _Float16* orow = O + ((long)b*SEQ + (qs_[s] + q31))*DM + h*64;
#pragma unroll
    for (int nd = 0; nd < 2; ++nd)
#pragma unroll
      for (int g = 0; g < 4; ++g) {
        half2v lo  = (half2v)__builtin_amdgcn_cvt_pkrtz(oacc[s][nd][4*g+0]*rl, oacc[s][nd][4*g+1]*rl);
        half2v hi2 = (half2v)__builtin_amdgcn_cvt_pkrtz(oacc[s][nd][4*g+2]*rl, oacc[s][nd][4*g+3]*rl);
        half4 o4 = __builtin_shufflevector(lo, hi2, 0, 1, 2, 3);
        *(half4*)&orow[nd*32 + g*8 + 4*hi] = o4;
      }
  }
}

extern "C" void kernel_launch(void* const* d_in, const int* in_sizes, int n_in,
                              void* d_out, int out_size, void* d_ws, size_t ws_size,
                              hipStream_t stream) {
  const float* x  = (const float*)d_in[0];
  const float* Wq = (const float*)d_in[1];
  const float* Wk = (const float*)d_in[2];
  const float* Wv = (const float*)d_in[3];
  const float* Wo = (const float*)d_in[4];
  const int*   tp = (const int*)d_in[5];
  float* out = (float*)d_out;

  char* ws = (char*)d_ws;
  _Float16* xh   = (_Float16*)(ws);                  // 16 MB  [8192][1024]
  _Float16* Wqkv = (_Float16*)(ws + (16u << 20));    //  6 MB  [3072][1024]
  _Float16* Woh  = (_Float16*)(ws + (22u << 20));    //  2 MB  [1024][1024]
  _Float16* Qb   = (_Float16*)(ws + (24u << 20));    // 16 MB  [64][2048][64]
  _Float16* Kb   = (_Float16*)(ws + (40u << 20));    // 16 MB
  _Float16* Vtb  = (_Float16*)(ws + (56u << 20));    // 16 MB  [64][64][2048]
  _Float16* attn = (_Float16*)(ws + (72u << 20));    // 16 MB  [8192][1024]

  cvtAll<<<12288, 256, 0, stream>>>(x, Wq, Wk, Wv, Wo, xh, Wqkv, Woh);

  gemm_hk<0><<<dim3(64, 24), 256, 0, stream>>>(xh, Wqkv, Qb, Kb, Vtb, nullptr, tp);
  fattn<<<dim3(64, 16), 128, 0, stream>>>(Qb, Kb, Vtb, attn);
  gemm_hk<1><<<dim3(64, 8), 256, 0, stream>>>(attn, Woh, nullptr, nullptr, nullptr, out, nullptr);
}

// Round 20
// 167.386 us; speedup vs baseline: 1.0568x; 1.0568x over previous
//
#include <hip/hip_runtime.h>
#include <hip/hip_fp16.h>

typedef _Float16 half8 __attribute__((ext_vector_type(8)));
typedef _Float16 half4 __attribute__((ext_vector_type(4)));
typedef _Float16 half2v __attribute__((ext_vector_type(2)));
typedef float f32x4 __attribute__((ext_vector_type(4)));
typedef float f32x8v __attribute__((ext_vector_type(8)));
typedef float f32x16 __attribute__((ext_vector_type(16)));

#define SEQ   2048
#define DM    1024
#define NH    16
#define HD    64
#define BSZ   4

#if __has_builtin(__builtin_amdgcn_exp2f)
#define EXP2(x) __builtin_amdgcn_exp2f(x)
#else
#define EXP2(x) exp2f(x)
#endif

// Q pre-scale: (1/sqrt(64)) * log2(e)  -> scores land in log2 domain
#define QSCALE 0.1803368801f
// log2(10000)/32
#define ROPE_C 0.41524101186f

// async global->LDS, 16B per lane. LDS dest = wave-uniform base + lane*16.
__device__ __forceinline__ void gload16(const void* g, void* l) {
  __builtin_amdgcn_global_load_lds((const __attribute__((address_space(1))) void*)g,
                                   (__attribute__((address_space(3))) void*)l,
                                   16, 0, 0);
}

// ---------------- fp32 -> fp16 convert: x + all 4 weights in ONE launch -------------
// items are float4/half4 quads. [0, 2097152) -> xh; then 4 x 262144 -> Wqkv, Woh.
__global__ void cvtAll(const float* __restrict__ x,
                       const float* __restrict__ s0, const float* __restrict__ s1,
                       const float* __restrict__ s2, const float* __restrict__ s3,
                       _Float16* __restrict__ xh, _Float16* __restrict__ dqkv,
                       _Float16* __restrict__ dO) {
  const int i = blockIdx.x * blockDim.x + threadIdx.x;
  const float* src;
  _Float16* dst;
  int idx;
  if (i < 2097152) {
    src = x; dst = xh; idx = i;
  } else {
    const int j = i - 2097152;
    const int which = j >> 18;            // 0..3
    idx = j & 262143;
    src = (which == 0) ? s0 : (which == 1) ? s1 : (which == 2) ? s2 : s3;
    dst = (which < 3) ? (dqkv + (long)which * (1u << 20)) : dO;
  }
  float4 v = ((const float4*)src)[idx];
  half4 o = { (_Float16)v.x, (_Float16)v.y, (_Float16)v.z, (_Float16)v.w };
  ((half4*)dst)[idx] = o;
}

// ---------------- GEMM: C = A * B^T, A[M][1024] f16, B[N][1024] f16 ----------------
// r15/r18 best-known config: 128x128 tile, 4 waves (2x2), BK=32, 16x16x32 f16 MFMA,
// 2-phase 32KB double-buffer (4 blocks/CU) + r12 zero-conflict slab swizzle
// (BANK_CONFLICT=0 verified). Campaign r11-r16 (depth-2 vmcnt, swizzle, wide tile,
// 8-phase) established ~700TF as this K=1024 shape's practical plateau.
// Slab layout: byte(row,g) = slab*2048 + (row>>1)*128 + ((((row&1)<<2)|g)^((row>>1)&7))*16,
// staged via linear-dest global_load_lds with inverse permutation on the per-lane
// GLOBAL source (rule #21).
// MODE 0: QKV epilogue with FUSED RoPE -> Q(scaled)[bh][s][64], K[bh][s][64],
//         Vt[bh][64][s] (f16).  MODE 1: plain f32 store to out[M][1024]
template<int MODE>
__global__ __launch_bounds__(256)
void gemm_hk(const _Float16* __restrict__ A, const _Float16* __restrict__ B,
             _Float16* __restrict__ oQ, _Float16* __restrict__ oK,
             _Float16* __restrict__ oVt, float* __restrict__ oF,
             const int* __restrict__ tp) {
  __shared__ _Float16 As[2][128*32];
  __shared__ _Float16 Bs[2][128*32];
  const int tid  = threadIdx.x;
  const int wid  = tid >> 6, lane = tid & 63;
  const int wm   = wid >> 1, wn = wid & 1;
  const int fr   = lane & 15, fg = lane >> 4;
  const long m0  = (long)blockIdx.x * 128;
  const long n0  = (long)blockIdx.y * 128;
  const int sg    = (lane & 7) ^ ((lane >> 3) & 7);
  const int srowl = 2*(lane >> 3) + (sg >> 2);      // row within 16-row group
  const int scol  = (sg & 3) * 8;                   // halfs
  const _Float16* ga0 = A + (m0 + wid*32 + srowl) * 1024 + scol;
  const _Float16* gb0 = B + (n0 + wid*32 + srowl) * 1024 + scol;
  const int lofs = wid*32*32;

  f32x4 acc[4][4] = {};

  auto ldfrag = [&](const char* base, int R) -> half8 {
    const int r = R & 31, r2 = r >> 1;
    return *(const half8*)(base + (R >> 5)*2048 + r2*128 +
                           (((((r & 1) << 2) | fg) ^ (r2 & 7)) << 4));
  };

  // prologue: stage k0=0 into buf 0
  gload16(ga0,           &As[0][lofs]);
  gload16(ga0 + 16*1024, &As[0][lofs + 16*32]);
  gload16(gb0,           &Bs[0][lofs]);
  gload16(gb0 + 16*1024, &Bs[0][lofs + 16*32]);
  __syncthreads();

  int cur = 0;
  for (int k0 = 0; k0 < 1024; k0 += 32) {
    if (k0 + 32 < 1024) {
      gload16(ga0 + k0 + 32,           &As[cur^1][lofs]);
      gload16(ga0 + k0 + 32 + 16*1024, &As[cur^1][lofs + 16*32]);
      gload16(gb0 + k0 + 32,           &Bs[cur^1][lofs]);
      gload16(gb0 + k0 + 32 + 16*1024, &Bs[cur^1][lofs + 16*32]);
    }
    const char* Ab = (const char*)&As[cur][0];
    const char* Bb = (const char*)&Bs[cur][0];
    half8 af[4], bf[4];
#pragma unroll
    for (int i = 0; i < 4; ++i) {
      af[i] = ldfrag(Ab, wm*64 + i*16 + fr);
      bf[i] = ldfrag(Bb, wn*64 + i*16 + fr);
    }
    __builtin_amdgcn_s_setprio(1);
#pragma unroll
    for (int i = 0; i < 4; ++i)
#pragma unroll
      for (int j = 0; j < 4; ++j)
        acc[i][j] = __builtin_amdgcn_mfma_f32_16x16x32_f16(af[i], bf[j], acc[i][j], 0, 0, 0);
    __builtin_amdgcn_s_setprio(0);
    __syncthreads();
    cur ^= 1;
  }

  if (MODE == 0) {
    const int which = (int)(n0 >> 10);
    const int nloc0 = ((int)n0 & 1023) + wn*64;
    const bool odd = fr & 1;
#pragma unroll
    for (int i = 0; i < 4; ++i) {
      const long r0 = m0 + wm*64 + i*16 + fg*4;
      const int  bb = (int)(r0 >> 11);
      const int  s  = (int)(r0 & 2047);
#pragma unroll
      for (int j = 0; j < 4; ++j) {
        const int nl = nloc0 + j*16 + fr;
        const int h  = nl >> 6, d = nl & 63;
        const long bh = (long)(bb*NH + h);
        if (which == 2) {
          half4 pk = { (_Float16)acc[i][j][0], (_Float16)acc[i][j][1],
                       (_Float16)acc[i][j][2], (_Float16)acc[i][j][3] };
          *(half4*)&oVt[(bh*HD + d)*SEQ + s] = pk;   // s % 4 == 0, 8B aligned
        } else {
          // fused RoPE: pair (2k,2k+1) lives in lanes (fr, fr^1), same (i,j,r)
          const float inv = exp2f(-ROPE_C * (float)(d >> 1));
#pragma unroll
          for (int r = 0; r < 4; ++r) {
            const float v = acc[i][j][r];
            const float p = __shfl_xor(v, 1);
            float sn, cs;
            __sincosf((float)tp[s + r] * inv, &sn, &cs);
            const float out = odd ? (v*cs + p*sn) : (v*cs - p*sn);
            if (which == 0)
              oQ[(bh*SEQ + s + r)*HD + d] = (_Float16)(out * QSCALE);
            else
              oK[(bh*SEQ + s + r)*HD + d] = (_Float16)out;
          }
        }
      }
    }
  } else {
#pragma unroll
    for (int i = 0; i < 4; ++i) {
      const long r0 = m0 + wm*64 + i*16 + fg*4;
#pragma unroll
      for (int j = 0; j < 4; ++j) {
        const long col = n0 + wn*64 + j*16 + fr;
#pragma unroll
        for (int r = 0; r < 4; ++r)
          oF[(r0 + r)*DM + col] = acc[i][j][r];
      }
    }
  }
}

// ---------------- causal flash attention (r10/r15/r18 best: 32x32, P-in-register) ---
// grid (BH=64, 8), 256 threads (4 waves). Wave = 32 heavy + 32 light q-rows
// (paired tiles (15-y), y). S^T = mfma(K,Q) with K rows read through PI(m) =
// swap bits 2<->3 of m. Lane (q31,hi) register r = 8*ks+i holds
// S[kv = kvb + i + 8*hi + 16*ks] — exactly the PV B-fragment layout, so P never
// touches LDS. Mask relabel: kvl(r,hi) = (r&3) + 4*((r>>2)&1) + 8*hi + 16*(r>>3).
// O^T = mfma(V,P). LDS = 32KB (KV dbuf only). Stats lane-local, 1 shuffle.
// Local optimum confirmed from four directions: registers-up (r3/r13), operand
// sharing (r17), block-shape-down (r19) all regressed vs this form.
__global__ __launch_bounds__(256, 2)
void fattn(const _Float16* __restrict__ Q, const _Float16* __restrict__ K,
           const _Float16* __restrict__ Vt, _Float16* __restrict__ O) {
  __shared__ _Float16 Ks[2][64*64];
  __shared__ _Float16 Vs[2][64*64];
  const int tid = threadIdx.x, wid = tid >> 6, lane = tid & 63;
  const int q31 = lane & 31, hi = lane >> 5;
  const int qp  = (q31 & 19) | ((q31 & 4) << 1) | ((q31 & 8) >> 1);  // swap bits 2,3
  const int bh = blockIdx.x, b = bh >> 4, h = bh & 15;
  const int y = blockIdx.y;              // 0..7
  const int qs_[2] = { (15 - y)*128 + wid*32, y*128 + wid*32 };
  const _Float16* Qb = Q + (long)bh * SEQ * HD;
  const _Float16* Kb = K + (long)bh * SEQ * HD;
  const _Float16* Vb = Vt + (long)bh * HD * SEQ;

  half8 qf[2][4];                        // [set][d-chunk16]
#pragma unroll
  for (int s = 0; s < 2; ++s)
#pragma unroll
    for (int c = 0; c < 4; ++c)
      qf[s][c] = *(const half8*)&Qb[(qs_[s] + q31)*HD + c*16 + hi*8];

  f32x16 oacc[2][2] = {};                // [set][nd]
  float m_s[2] = { -1e30f, -1e30f }, l_s[2] = { 0.f, 0.f };

  const int srow = lane >> 3;
  const int sc16 = (lane & 7) ^ srow;
  const int r1 = wid*16 + srow, r2 = r1 + 8;

  const int nt = (15 - y)*2 + 2;

  gload16(Kb + (long)r1*HD + sc16*8, &Ks[0][(wid*16)*64]);
  gload16(Kb + (long)r2*HD + sc16*8, &Ks[0][(wid*16 + 8)*64]);
  gload16(Vb + (long)r1*SEQ + sc16*8, &Vs[0][(wid*16)*64]);
  gload16(Vb + (long)r2*SEQ + sc16*8, &Vs[0][(wid*16 + 8)*64]);
  __syncthreads();

  int cur = 0;
  for (int t = 0; t < nt; ++t) {
    const int kv0 = t * 64;

    if (t + 1 < nt) {
      const int nkv = kv0 + 64;
      gload16(Kb + (long)(nkv + r1)*HD + sc16*8, &Ks[cur^1][(wid*16)*64]);
      gload16(Kb + (long)(nkv + r2)*HD + sc16*8, &Ks[cur^1][(wid*16 + 8)*64]);
      gload16(Vb + (long)r1*SEQ + nkv + sc16*8,  &Vs[cur^1][(wid*16)*64]);
      gload16(Vb + (long)r2*SEQ + nkv + sc16*8,  &Vs[cur^1][(wid*16 + 8)*64]);
    }

    const char* Kc = (const char*)&Ks[cur][0];
    const char* Vc = (const char*)&Vs[cur][0];

#pragma unroll
    for (int hh = 0; hh < 2; ++hh) {
      const int kvb = kv0 + 32*hh;
#pragma unroll
      for (int s = 0; s < 2; ++s) {
        const int qs0 = qs_[s];
        if (kvb > qs0 + 31) continue;

        f32x16 sa = {};
        __builtin_amdgcn_s_setprio(1);
#pragma unroll
        for (int c = 0; c < 4; ++c) {
          const int row = 32*hh + qp;
          const half8 kf = *(const half8*)(Kc + row*128 + ((c*32 + hi*16) ^ ((row & 7) << 4)));
          sa = __builtin_amdgcn_mfma_f32_32x32x16_f16(kf, qf[s][c], sa, 0, 0, 0);
        }
        __builtin_amdgcn_s_setprio(0);

        if (kvb + 31 > qs0) {
          const int thr = qs0 + q31 - kvb - 8*hi;
#pragma unroll
          for (int r = 0; r < 16; ++r) {
            const int cr = (r & 3) + 4*((r >> 2) & 1) + 16*(r >> 3);
            if (cr > thr) sa[r] = -1e30f;
          }
        }

        f32x8v mx8;
#pragma unroll
        for (int i = 0; i < 8; ++i) mx8[i] = fmaxf(sa[i], sa[i+8]);
        f32x4 mx4;
#pragma unroll
        for (int i = 0; i < 4; ++i) mx4[i] = fmaxf(mx8[i], mx8[i+4]);
        float pm = fmaxf(fmaxf(mx4[0], mx4[1]), fmaxf(mx4[2], mx4[3]));
        pm = fmaxf(pm, __shfl_xor(pm, 32));

        if (!__all(pm <= m_s[s] + 8.0f)) {
          const float mn = fmaxf(m_s[s], pm);
          const float fac = EXP2(m_s[s] - mn);
          m_s[s] = mn;
          l_s[s] *= fac;
          oacc[s][0] *= fac;
          oacc[s][1] *= fac;
        }
        const float mrow = m_s[s];

#pragma unroll
        for (int r = 0; r < 16; ++r) sa[r] = EXP2(sa[r] - mrow);

        f32x8v s8;
#pragma unroll
        for (int i = 0; i < 8; ++i) s8[i] = sa[i] + sa[i+8];
        f32x4 s4v;
#pragma unroll
        for (int i = 0; i < 4; ++i) s4v[i] = s8[i] + s8[i+4];
        float ps = (s4v[0] + s4v[1]) + (s4v[2] + s4v[3]);
        ps += __shfl_xor(ps, 32);
        l_s[s] += ps;

        half8 pf0, pf1;
#pragma unroll
        for (int g = 0; g < 4; ++g) {
          half2v t0 = (half2v)__builtin_amdgcn_cvt_pkrtz(sa[2*g],   sa[2*g+1]);
          half2v t1 = (half2v)__builtin_amdgcn_cvt_pkrtz(sa[8+2*g], sa[8+2*g+1]);
          pf0[2*g]   = t0[0];  pf0[2*g+1] = t0[1];
          pf1[2*g]   = t1[0];  pf1[2*g+1] = t1[1];
        }

        __builtin_amdgcn_s_setprio(1);
#pragma unroll
        for (int ks = 0; ks < 2; ++ks) {
          const half8 pf = ks ? pf1 : pf0;
#pragma unroll
          for (int nd = 0; nd < 2; ++nd) {
            const int row = nd*32 + q31;
            const half8 vf = *(const half8*)(Vc + row*128 +
                              ((hh*64 + ks*32 + hi*16) ^ ((row & 7) << 4)));
            oacc[s][nd] = __builtin_amdgcn_mfma_f32_32x32x16_f16(vf, pf, oacc[s][nd], 0, 0, 0);
          }
        }
        __builtin_amdgcn_s_setprio(0);
      }
    }

    __syncthreads();
    cur ^= 1;
  }

#pragma unroll
  for (int s = 0; s < 2; ++s) {
    const float rl = __builtin_amdgcn_rcpf(l_s[s]);
    _Float16* orow = O + ((long)b*SEQ + (qs_[s] + q31))*DM + h*64;
#pragma unroll
    for (int nd = 0; nd < 2; ++nd)
#pragma unroll
      for (int g = 0; g < 4; ++g) {
        half2v lo  = (half2v)__builtin_amdgcn_cvt_pkrtz(oacc[s][nd][4*g+0]*rl, oacc[s][nd][4*g+1]*rl);
        half2v hi2 = (half2v)__builtin_amdgcn_cvt_pkrtz(oacc[s][nd][4*g+2]*rl, oacc[s][nd][4*g+3]*rl);
        half4 o4 = __builtin_shufflevector(lo, hi2, 0, 1, 2, 3);
        *(half4*)&orow[nd*32 + g*8 + 4*hi] = o4;
      }
  }
}

extern "C" void kernel_launch(void* const* d_in, const int* in_sizes, int n_in,
                              void* d_out, int out_size, void* d_ws, size_t ws_size,
                              hipStream_t stream) {
  const float* x  = (const float*)d_in[0];
  const float* Wq = (const float*)d_in[1];
  const float* Wk = (const float*)d_in[2];
  const float* Wv = (const float*)d_in[3];
  const float* Wo = (const float*)d_in[4];
  const int*   tp = (const int*)d_in[5];
  float* out = (float*)d_out;

  char* ws = (char*)d_ws;
  _Float16* xh   = (_Float16*)(ws);                  // 16 MB  [8192][1024]
  _Float16* Wqkv = (_Float16*)(ws + (16u << 20));    //  6 MB  [3072][1024]
  _Float16* Woh  = (_Float16*)(ws + (22u << 20));    //  2 MB  [1024][1024]
  _Float16* Qb   = (_Float16*)(ws + (24u << 20));    // 16 MB  [64][2048][64]
  _Float16* Kb   = (_Float16*)(ws + (40u << 20));    // 16 MB
  _Float16* Vtb  = (_Float16*)(ws + (56u << 20));    // 16 MB  [64][64][2048]
  _Float16* attn = (_Float16*)(ws + (72u << 20));    // 16 MB  [8192][1024]

  cvtAll<<<12288, 256, 0, stream>>>(x, Wq, Wk, Wv, Wo, xh, Wqkv, Woh);

  gemm_hk<0><<<dim3(64, 24), 256, 0, stream>>>(xh, Wqkv, Qb, Kb, Vtb, nullptr, tp);
  fattn<<<dim3(64, 8), 256, 0, stream>>>(Qb, Kb, Vtb, attn);
  gemm_hk<1><<<dim3(64, 8), 256, 0, stream>>>(attn, Woh, nullptr, nullptr, nullptr, out, nullptr);
}